// Round 11
// baseline (539.952 us; speedup 1.0000x reference)
//
#include <hip/hip_runtime.h>
#include <hip/hip_bf16.h>
#include <hip/hip_cooperative_groups.h>
#include <math.h>

namespace cg = cooperative_groups;

// TreeLSTM, B=8, L=4096, D=300, H=128, 12 levels. Round 11:
// EMPIRICAL RULE (R7-R10): 512-thr blocks compile to 128 VGPRs regardless of
// launch_bounds -> Wfr[5][8] (160 VGPR) spills to scratch -> ~100us/launch.
// 256-thr blocks with (256,2) get the 256 cap and hold Wfr (R7's fast levels).
// This round: ONE cooperative kernel (256 blocks x 256 thr, (256,2)) runs ALL
// 12 levels: W-slice -> LDS -> VGPR fragments once; 64-row tiles strided by
// row-slot; fused LSTM epilogue; grid.sync between levels. 3 launches total.
// Chunk-major layouts: unit u = [c=k/8][row] of 16B (8 bf16).

typedef __attribute__((ext_vector_type(8))) short bfrag8;   // 8 bf16 = 4 VGPRs
typedef __attribute__((ext_vector_type(4))) float f32x4;
typedef __attribute__((ext_vector_type(4))) short s16x4;

__device__ __forceinline__ float sigf(float x) { return 1.0f / (1.0f + __expf(-x)); }
__device__ __forceinline__ short f2bf(float f) {
    __hip_bfloat16 h = __float2bfloat16(f);
    return *reinterpret_cast<short*>(&h);
}
#define GLDS(gp, lp) __builtin_amdgcn_global_load_lds( \
    (const __attribute__((address_space(1))) void*)(gp), \
    (__attribute__((address_space(3))) void*)(lp), 16, 0, 0)

// ---------------- prep: weight reorder + x conversion, one launch ----------------
__global__ __launch_bounds__(256) void prep_kernel(
    const float* __restrict__ W_l, const float* __restrict__ W_r,
    const float* __restrict__ W_leaf, const float* __restrict__ x,
    short* __restrict__ Wcat_ch, short* __restrict__ Wleaf_ch,
    short* __restrict__ xbf)
{
    __shared__ short Ls[64 * 328];
    const int tid = threadIdx.x;
    const int b = blockIdx.x;
    if (b < 512) {
        // convx: x fp32 [32768][300] -> xbf chunk-major [40][32768] units
        const int R0 = b * 64;
        for (int i = tid; i < 64 * 75; i += 256) {
            int r = i / 75, q = i - r * 75;
            f32x4 v = *(const f32x4*)(x + (size_t)(R0 + r) * 300 + q * 4);
            s16x4 o;
            #pragma unroll
            for (int t = 0; t < 4; ++t) o[t] = f2bf(v[t]);
            *(s16x4*)(Ls + r * 328 + q * 4) = o;
        }
        for (int i = tid; i < 64 * 20; i += 256) {
            int r = i / 20, q = i - r * 20;
            Ls[r * 328 + 300 + q] = 0;
        }
        __syncthreads();
        for (int i = tid; i < 40 * 64; i += 256) {
            int c = i >> 6, r = i & 63;
            bfrag8 v = *(const bfrag8*)(Ls + r * 328 + c * 8);
            *(bfrag8*)(xbf + ((size_t)c * 32768 + R0 + r) * 8) = v;
        }
        return;
    }
    int idx = (b - 512) * 256 + tid;
    if (idx < 163840) {
        int n = idx >> 8, k = idx & 255;
        float v = (k < 128) ? W_l[k * 640 + n] : W_r[(k - 128) * 640 + n];
        Wcat_ch[(((size_t)(k >> 3)) * 640 + n) * 8 + (k & 7)] = f2bf(v);
        return;
    }
    idx -= 163840;
    if (idx < 81920) {
        int n = idx / 320, k = idx - n * 320;
        short v = (k < 300) ? f2bf(W_leaf[k * 256 + n]) : (short)0;
        Wleaf_ch[(((size_t)(k >> 3)) * 256 + n) * 8 + (k & 7)] = v;
    }
}

// ---------------- leaf: [32768,320]@[320,256] + bias, split h/c (double-buffered) ----------------
__global__ __launch_bounds__(256, 2) void leaf_kernel(
    const short* __restrict__ A, const short* __restrict__ B,
    const float* __restrict__ bleaf,
    short* __restrict__ hD,       // level-1 A, chunk layout [32][16384] units
    float* __restrict__ cD)       // [32768][128] fp32
{
    __shared__ short Als[2][8 * 128 * 8];
    __shared__ short Bls[2][8 * 128 * 8];
    const int tid  = threadIdx.x;
    const int w    = tid >> 6, lane = tid & 63;
    const int quad = lane >> 4, l16 = lane & 15;
    const int mBlk = blockIdx.x * 128, nBlk = blockIdx.y * 128;
    const int waveM = (w >> 1) * 64, waveN = (w & 1) * 64;

    f32x4 acc[4][4] = {};

    auto stage = [&](int k0, int buf) {
        #pragma unroll
        for (int q = 0; q < 4; ++q) {
            int rr = w * 4 + q, cl = rr >> 1, rh = rr & 1;
            GLDS(A + ((size_t)(k0 + cl) * 32768 + mBlk + rh * 64 + lane) * 8,
                 (char*)Als[buf] + rr * 1024);
            GLDS(B + ((size_t)(k0 + cl) * 256 + nBlk + rh * 64 + lane) * 8,
                 (char*)Bls[buf] + rr * 1024);
        }
    };

    stage(0, 0);
    #pragma unroll
    for (int s = 0; s < 5; ++s) {
        __syncthreads();
        if (s < 4) stage((s + 1) * 8, (s + 1) & 1);
        const short* Ab = Als[s & 1];
        const short* Bb = Bls[s & 1];
        #pragma unroll
        for (int ks = 0; ks < 2; ++ks) {
            int ca = ks * 4 + quad;
            bfrag8 af[4], bf[4];
            #pragma unroll
            for (int i = 0; i < 4; ++i)
                af[i] = *(const bfrag8*)(Ab + (ca * 128 + waveM + i * 16 + l16) * 8);
            #pragma unroll
            for (int jn = 0; jn < 4; ++jn)
                bf[jn] = *(const bfrag8*)(Bb + (ca * 128 + waveN + jn * 16 + l16) * 8);
            #pragma unroll
            for (int i = 0; i < 4; ++i)
                #pragma unroll
                for (int jn = 0; jn < 4; ++jn)
                    acc[i][jn] = __builtin_amdgcn_mfma_f32_16x16x32_bf16(
                                     af[i], bf[jn], acc[i][jn], 0, 0, 0);
        }
    }

    #pragma unroll
    for (int i = 0; i < 4; ++i) {
        int row0 = mBlk + waveM + i * 16 + quad * 4;
        #pragma unroll
        for (int jn = 0; jn < 4; ++jn) {
            int col = nBlk + waveN + jn * 16 + l16;
            float bv = bleaf[col];
            #pragma unroll
            for (int rg = 0; rg < 4; ++rg) {
                float v = acc[i][jn][rg] + bv;
                int m = row0 + rg;
                if (nBlk == 0) {
                    int hc = col;
                    hD[(((size_t)((m & 1) * 16 + (hc >> 3))) * 16384 + (m >> 1)) * 8
                       + (hc & 7)] = f2bf(v);
                } else {
                    cD[(size_t)m * 128 + (col - 128)] = v;
                }
            }
        }
    }
}

// ---------------- ALL 12 levels, one cooperative launch ----------------
// 256 blocks x 256 thr, (256,2) -> 256-VGPR cap (the R7-proven no-spill shape).
// Block (rs = bid>>3, j = bid&7): wave w = m-tile (16 rows); j's 80-n W-slice
// staged to LDS once -> Wfr[5][8] in VGPRs for all levels. Per level: 64-row
// tiles strided by rs (32 slots); A via GLDS; fused epilogue; grid.sync.
__global__ __launch_bounds__(256, 2) void coop_levels_kernel(
    const short* __restrict__ Wch,    // [32][640] chunk units
    const float* __restrict__ bias,   // [640]
    short* hA, float* c0, short* hB, float* c1,
    float* __restrict__ out)
{
    cg::grid_group grid = cg::this_grid();
    __shared__ short Wlds[32 * 80 * 8];   // 40 KB, [c][n'=g*16+hh]
    __shared__ short Als[32 * 64 * 8];    // 32 KB, [c][row64]
    const int tid  = threadIdx.x;
    const int w    = tid >> 6, lane = tid & 63;
    const int quad = lane >> 4, l16 = lane & 15;
    const int j  = blockIdx.x & 7;
    const int rs = blockIdx.x >> 3;
    const int h  = j * 16 + l16;

    // ---- stage W slice: 40 rounds of 1KB (10/wave), per-lane global scatter ----
    #pragma unroll
    for (int q = 0; q < 10; ++q) {
        int r = w * 10 + q;
        int u = r * 64 + lane;              // flat unit in [c][80] layout
        int c = u / 80, np = u - c * 80;
        int g = np >> 4, hh = np & 15;
        GLDS(Wch + ((size_t)c * 640 + g * 128 + j * 16 + hh) * 8,
             (char*)Wlds + r * 1024);
    }
    __syncthreads();
    // ---- W fragments LDS -> VGPR, once for all 12 levels ----
    bfrag8 Wfr[5][8];
    #pragma unroll
    for (int g = 0; g < 5; ++g)
        #pragma unroll
        for (int s = 0; s < 8; ++s)
            Wfr[g][s] = *(const bfrag8*)(Wlds + (((s * 4 + quad) * 80) + g * 16 + l16) * 8);
    const float bi  = bias[h],       bfl = bias[128 + h], bfr_ = bias[256 + h];
    const float bo  = bias[384 + h], bg  = bias[512 + h];

    const short* hin = hA; const float* cin = c0;
    short* hout = hB; float* cout = c1;
    int M = 16384;

    for (int lev = 1; lev <= 12; ++lev) {
        float* of = (lev == 12) ? out : nullptr;
        const int Mn = M >> 1;
        const int T = (M + 63) >> 6;
        for (int t = rs; t < T; t += 32) {
            const int tb = t * 64;
            __syncthreads();                   // Als reuse guard
            // ---- stage A tile: 8 GLDS per wave ----
            {
                int row = tb + lane; if (row >= M) row = 0;
                #pragma unroll
                for (int s = 0; s < 8; ++s)
                    GLDS(hin + ((size_t)(s * 4 + w) * M + row) * 8,
                         (char*)Als + (s * 4 + w) * 1024);
            }
            __syncthreads();

            // ---- K-loop: 8 ksteps x (1 ds_read_b128 + 5 MFMA) ----
            f32x4 acc[5] = {};
            #pragma unroll
            for (int s = 0; s < 8; ++s) {
                bfrag8 af = *(const bfrag8*)(Als + ((s * 4 + quad) * 64
                                                    + w * 16 + l16) * 8);
                #pragma unroll
                for (int g = 0; g < 5; ++g)
                    acc[g] = __builtin_amdgcn_mfma_f32_16x16x32_bf16(
                                 af, Wfr[g][s], acc[g], 0, 0, 0);
            }

            // ---- fused LSTM epilogue ----
            #pragma unroll
            for (int rg = 0; rg < 4; ++rg) {
                int m = tb + w * 16 + quad * 4 + rg;
                if (m < M) {
                    float gi  = acc[0][rg] + bi;
                    float gfl = acc[1][rg] + bfl;
                    float gfr = acc[2][rg] + bfr_;
                    float go  = acc[3][rg] + bo;
                    float gg  = acc[4][rg] + bg;
                    float cl  = cin[(size_t)(2 * m) * 128 + h];
                    float cr  = cin[(size_t)(2 * m + 1) * 128 + h];
                    float cn  = sigf(gfl) * cl + sigf(gfr) * cr + sigf(gi) * tanhf(gg);
                    float hn  = sigf(go) * tanhf(cn);
                    if (of) {
                        of[(size_t)m * 128 + h] = hn;
                    } else {
                        hout[(((size_t)((m & 1) * 16 + (h >> 3))) * Mn + (m >> 1)) * 8
                             + (h & 7)] = f2bf(hn);
                        cout[(size_t)m * 128 + h] = cn;
                    }
                }
            }
        }
        grid.sync();
        const short* nh = hin; const float* nc = cin;
        hin = hout; cin = cout;
        hout = (short*)nh; cout = (float*)nc;
        M >>= 1;
    }
}

extern "C" void kernel_launch(void* const* d_in, const int* in_sizes, int n_in,
                              void* d_out, int out_size, void* d_ws, size_t ws_size,
                              hipStream_t stream)
{
    const float* x      = (const float*)d_in[0];
    const float* W_leaf = (const float*)d_in[1];
    const float* b_leaf = (const float*)d_in[2];
    const float* W_l    = (const float*)d_in[3];
    const float* W_r    = (const float*)d_in[4];
    const float* b      = (const float*)d_in[5];
    float* out = (float*)d_out;

    // workspace (~59 MB)
    char* p = (char*)d_ws;
    short* xbf   = (short*)p; p += (size_t)40 * 32768 * 16;        // 21.0 MB
    short* hA    = (short*)p; p += (size_t)32 * 16384 * 16 + 1024; //  8.4 MB
    short* hB    = (short*)p; p += (size_t)32 * 8192 * 16 + 1024;  //  4.2 MB
    float* c0    = (float*)p; p += (size_t)32768 * 128 * 4;        // 16.8 MB
    float* c1    = (float*)p; p += (size_t)16384 * 128 * 4;        //  8.4 MB
    short* WcatC = (short*)p; p += (size_t)32 * 640 * 16;          // 320 KB
    short* WlfC  = (short*)p; p += (size_t)40 * 256 * 16;          // 160 KB

    prep_kernel<<<1472, 256, 0, stream>>>(W_l, W_r, W_leaf, x, WcatC, WlfC, xbf);
    leaf_kernel<<<dim3(256, 2), 256, 0, stream>>>(xbf, WlfC, b_leaf, hA, c0);

    void* cargs[] = { (void*)&WcatC, (void*)&b, (void*)&hA, (void*)&c0,
                      (void*)&hB, (void*)&c1, (void*)&out };
    hipLaunchCooperativeKernel((void*)coop_levels_kernel, dim3(256), dim3(256),
                               cargs, 0, stream);
}